// Round 9
// baseline (91.262 us; speedup 1.0000x reference)
//
#include <hip/hip_runtime.h>
#include <math.h>

#define BDIM 4096
#define DDIM 128
#define EPSF 1e-12f
#define TI 128
#define TJ 64
#define NSPLIT 32
#define NSLICE (NSPLIT * 2)                 // 64: one slice per 32-col half
#define ITILES (BDIM / TI)                  // 32
#define JT 6                                // (3*64 tiles)/NSPLIT
#define FLT_BIG 3.402823466e+38f
#define MATSZ (BDIM * DDIM)                 // 524288

typedef __attribute__((ext_vector_type(8))) _Float16 f16x8;
typedef __attribute__((ext_vector_type(16))) float f32x16;

// global (pre-swizzled per-lane addr) -> linear LDS, 16B/lane
__device__ __forceinline__ void gload_lds16(const void* g, void* l) {
    __builtin_amdgcn_global_load_lds(
        (const __attribute__((address_space(1))) unsigned int*)(uintptr_t)g,
        (__attribute__((address_space(3))) unsigned int*)(unsigned int)(uintptr_t)l,
        16, 0, 0);
}

__device__ __forceinline__ unsigned int pack2h(float x, float y) {
    _Float16 hx = (_Float16)x, hy = (_Float16)y;
    unsigned short ux, uy;
    __builtin_memcpy(&ux, &hx, 2);
    __builtin_memcpy(&uy, &hy, 2);
    return (unsigned int)ux | ((unsigned int)uy << 16);
}

// ---------------- Kernel 0: fused fp16 convert + row norms + distance_pos ----
__global__ __launch_bounds__(256) void prep_kernel(
    const float* __restrict__ A, const float* __restrict__ P,
    const float* __restrict__ N, ushort* __restrict__ Xf,
    float* __restrict__ a2, float* __restrict__ p2,
    float* __restrict__ n2, float* __restrict__ dpos) {
    int row = (blockIdx.x * blockDim.x + threadIdx.x) >> 6;
    int lane = threadIdx.x & 63;
    if (row >= BDIM) return;
    const float2 av = *(const float2*)&A[row * DDIM + lane * 2];
    const float2 pv = *(const float2*)&P[row * DDIM + lane * 2];
    const float2 nv = *(const float2*)&N[row * DDIM + lane * 2];
    *(unsigned int*)&Xf[0 * MATSZ + row * DDIM + lane * 2] = pack2h(av.x, av.y);
    *(unsigned int*)&Xf[1 * MATSZ + row * DDIM + lane * 2] = pack2h(pv.x, pv.y);
    *(unsigned int*)&Xf[2 * MATSZ + row * DDIM + lane * 2] = pack2h(nv.x, nv.y);
    float sa = av.x * av.x + av.y * av.y;
    float sp = pv.x * pv.x + pv.y * pv.y;
    float sn = nv.x * nv.x + nv.y * nv.y;
    float dx = av.x - pv.x, dy = av.y - pv.y;
    float sd = dx * dx + dy * dy;
    #pragma unroll
    for (int off = 32; off; off >>= 1) {
        sa += __shfl_down(sa, off);
        sp += __shfl_down(sp, off);
        sn += __shfl_down(sn, off);
        sd += __shfl_down(sd, off);
    }
    if (lane == 0) {
        a2[row] = sa;
        p2[row] = sp;
        n2[row] = sn;
        dpos[row] = sqrtf(fmaxf(sd, EPSF));
    }
}

// stage one 64x128 fp16 tile into a linear LDS buffer; XOR-16-slot swizzle on
// the global source address (involution). 4 gload_lds per wave.
__device__ __forceinline__ void stage_Y(const ushort* g, int j0, ushort* dst,
                                        int w, int lane) {
    int sub = lane >> 4;
    int s = lane & 15;
    #pragma unroll
    for (int q = 0; q < 4; ++q) {
        int r = w * 16 + q * 4 + sub;
        int sp = s ^ (r & 15);
        gload_lds16(g + (size_t)(j0 + r) * DDIM + sp * 8,
                    dst + (w * 16 + q * 4) * DDIM);
    }
}

// ---------------- Kernel 1: fp16 MFMA min of (y2/2 - dot) ----------------
// grid (32 i-tiles, 32 splits), 256 thr = 4 waves; wave = 64 rows x 32 cols
// (2 acc chains share each B fragment). A frags direct from L2 (no staging);
// Y triple-buffered 3x16KB = 48KB -> 3 blocks/CU (12 waves/CU).
__global__ __launch_bounds__(256, 3) void minsq_kernel(
    const ushort* __restrict__ Xf,
    const float* __restrict__ a2, const float* __restrict__ p2,
    const float* __restrict__ n2, float* __restrict__ partial) {
    __shared__ __align__(16) ushort Y[3][TJ * DDIM];   // 48 KB

    const int tid = threadIdx.x;
    const int w = tid >> 6;
    const int lane = tid & 63;
    const int rg = w >> 1;    // 64-row group of the 128-row i-tile
    const int ch = w & 1;     // 32-col half of the 64-col j-tile
    const int iTile = blockIdx.x;
    const int split = blockIdx.y;
    const int i0 = iTile * TI;
    const int jt0 = split * JT;

    // stage tile 0 -> Y[0]
    stage_Y(Xf + (size_t)(jt0 >> 6) * MATSZ, (jt0 & 63) * TJ, Y[0], w, lane);

    // A fragments direct from global (L2-resident; prologue only)
    f16x8 a0[8], a1[8];
    {
        const ushort* r0 =
            Xf + (size_t)(i0 + rg * 64 + (lane & 31)) * DDIM + (lane >> 5) * 8;
        const ushort* r1 = r0 + 32 * DDIM;
        #pragma unroll
        for (int t = 0; t < 8; ++t) {
            a0[t] = *(const f16x8*)(r0 + t * 16);
            a1[t] = *(const f16x8*)(r1 + t * 16);
        }
    }
    // y2/2 per tile for this wave's 32 columns
    float y2h[JT];
    #pragma unroll
    for (int t = 0; t < JT; ++t) {
        int jt = jt0 + t, m = jt >> 6, tc = jt & 63;
        const float* y2g = (m == 0) ? a2 : ((m == 1) ? p2 : n2);
        y2h[t] = 0.5f * y2g[tc * TJ + ch * 32 + (lane & 31)];
    }

    float minv[2][16];
    #pragma unroll
    for (int rb = 0; rb < 2; ++rb)
        #pragma unroll
        for (int g = 0; g < 16; ++g) minv[rb][g] = FLT_BIG;

    #pragma unroll
    for (int t = 0; t < JT; ++t) {
        // depth-1 prefetch: stage tile t+1 into Y[(t+1)%3]
        if (t + 1 < JT) {
            int jn = jt0 + t + 1;
            stage_Y(Xf + (size_t)(jn >> 6) * MATSZ, (jn & 63) * TJ,
                    Y[(t + 1) % 3], w, lane);
            asm volatile("s_waitcnt vmcnt(4)" ::: "memory");  // tile t done
        } else {
            asm volatile("s_waitcnt vmcnt(0)" ::: "memory");
        }
        __builtin_amdgcn_sched_barrier(0);
        __builtin_amdgcn_s_barrier();     // all waves' tile t ready; also
        __builtin_amdgcn_sched_barrier(0);// fences writes vs t-2 readers

        const ushort* buf = Y[t % 3];
        const int rB = ch * 32 + (lane & 31);
        f32x16 acc0 = {}, acc1 = {};
        __builtin_amdgcn_s_setprio(1);
        #pragma unroll
        for (int k = 0; k < 8; ++k) {
            int sl = k * 2 + (lane >> 5);
            f16x8 b = *(const f16x8*)&buf[rB * DDIM + (sl ^ (rB & 15)) * 8];
            acc0 = __builtin_amdgcn_mfma_f32_32x32x16_f16(a0[k], b, acc0, 0, 0, 0);
            acc1 = __builtin_amdgcn_mfma_f32_32x32x16_f16(a1[k], b, acc1, 0, 0, 0);
        }
        __builtin_amdgcn_s_setprio(0);

        // epilogue: running min of (y2/2 - dot); diag exclusion on A/P mats
        {
            int jt = jt0 + t, m = jt >> 6, tc = jt & 63;
            float yh = y2h[t];
            if (m < 2 && (tc >> 1) == iTile) {
                int jg = tc * TJ + ch * 32 + (lane & 31);
                #pragma unroll
                for (int rb = 0; rb < 2; ++rb) {
                    #pragma unroll
                    for (int g = 0; g < 16; ++g) {
                        int rloc = (g & 3) + 8 * (g >> 2) + 4 * (lane >> 5);
                        int ig = i0 + rg * 64 + rb * 32 + rloc;
                        float d = (rb == 0) ? acc0[g] : acc1[g];
                        float cand = yh - d;
                        if (ig == jg) cand = FLT_BIG;
                        minv[rb][g] = fminf(minv[rb][g], cand);
                    }
                }
            } else {
                #pragma unroll
                for (int g = 0; g < 16; ++g) {
                    minv[0][g] = fminf(minv[0][g], yh - acc0[g]);
                    minv[1][g] = fminf(minv[1][g], yh - acc1[g]);
                }
            }
        }
    }

    // min over the 32 columns (within each 32-lane half)
    #pragma unroll
    for (int off = 1; off < 32; off <<= 1) {
        #pragma unroll
        for (int rb = 0; rb < 2; ++rb)
            #pragma unroll
            for (int g = 0; g < 16; ++g)
                minv[rb][g] = fminf(minv[rb][g], __shfl_xor(minv[rb][g], off));
    }
    if ((lane & 31) == 0) {
        int hi = lane >> 5;
        int slice = split * 2 + ch;
        #pragma unroll
        for (int rb = 0; rb < 2; ++rb) {
            #pragma unroll
            for (int g = 0; g < 16; ++g) {
                int rloc = (g & 3) + 8 * (g >> 2) + 4 * hi;
                int ig = i0 + rg * 64 + rb * 32 + rloc;
                partial[(size_t)ig * NSLICE + slice] = minv[rb][g];
            }
        }
    }
}

// ---------------- Kernel 2a: per-row loss, 16-block partial sums ------------
__global__ __launch_bounds__(256) void lossA_kernel(
    const float* __restrict__ partial, const float* __restrict__ a2,
    const float* __restrict__ dpos, float* __restrict__ bsum) {
    __shared__ float red[4];
    int i = blockIdx.x * 256 + threadIdx.x;
    const float4* pr = (const float4*)&partial[(size_t)i * NSLICE];
    float mv = FLT_BIG;
    #pragma unroll
    for (int q = 0; q < NSLICE / 4; ++q) {
        float4 v = pr[q];
        mv = fminf(mv, fminf(fminf(v.x, v.y), fminf(v.z, v.w)));
    }
    float h2 = a2[i] + 2.0f * mv;
    float hardest = sqrtf(fmaxf(h2, EPSF));
    float x = dpos[i] - hardest;
    float sum = fmaxf(x, 0.f) + log1pf(expf(-fabsf(x)));
    #pragma unroll
    for (int off = 32; off; off >>= 1) sum += __shfl_down(sum, off);
    if ((threadIdx.x & 63) == 0) red[threadIdx.x >> 6] = sum;
    __syncthreads();
    if (threadIdx.x == 0)
        bsum[blockIdx.x] = red[0] + red[1] + red[2] + red[3];
}

// ---------------- Kernel 2b: final scalar ----------------
__global__ void lossB_kernel(const float* __restrict__ bsum,
                             float* __restrict__ out) {
    float v = (threadIdx.x < 16) ? bsum[threadIdx.x] : 0.f;
    #pragma unroll
    for (int off = 32; off; off >>= 1) v += __shfl_down(v, off);
    if (threadIdx.x == 0) out[0] = v * (1.0f / BDIM);
}

extern "C" void kernel_launch(void* const* d_in, const int* in_sizes, int n_in,
                              void* d_out, int out_size, void* d_ws, size_t ws_size,
                              hipStream_t stream) {
    const float* A = (const float*)d_in[0];
    const float* P = (const float*)d_in[1];
    const float* N = (const float*)d_in[2];

    float* ws = (float*)d_ws;
    float* a2 = ws;                          // 4096
    float* p2 = ws + BDIM;                   // 4096
    float* n2 = ws + 2 * BDIM;               // 4096
    float* dpos = ws + 3 * BDIM;             // 4096
    float* bsum = ws + 4 * BDIM;             // 64 (16 used)
    float* partial = ws + 4 * BDIM + 64;     // BDIM * NSLICE (row-major)
    ushort* Xf = (ushort*)(partial + (size_t)BDIM * NSLICE);  // 3*524288 fp16

    prep_kernel<<<BDIM / 4, 256, 0, stream>>>(A, P, N, Xf, a2, p2, n2, dpos);
    dim3 grid2(ITILES, NSPLIT);
    minsq_kernel<<<grid2, 256, 0, stream>>>(Xf, a2, p2, n2, partial);
    lossA_kernel<<<16, 256, 0, stream>>>(partial, a2, dpos, bsum);
    lossB_kernel<<<1, 64, 0, stream>>>(bsum, (float*)d_out);
}

// Round 10
// 43.205 us; speedup vs baseline: 2.1123x; 2.1123x over previous
//
#include <hip/hip_runtime.h>
#include <math.h>

#define BDIM 4096
#define DDIM 128
#define EPSF 1e-12f
#define TI 128
#define TJ 64
#define NSPLIT 16
#define NSLICE (NSPLIT * 2)                 // one slice per column-half wave
#define ITILES (BDIM / TI)                  // 32
#define JT 12                               // tiles per split (16*12 = 192 total)
#define FLT_BIG 3.402823466e+38f
#define MATSZ (BDIM * DDIM)                 // 524288
#define YBUF (TJ * DDIM)                    // 8192 ushorts = 16 KB

typedef __attribute__((ext_vector_type(8))) _Float16 f16x8;
typedef __attribute__((ext_vector_type(16))) float f32x16;

// global (pre-swizzled per-lane addr) -> linear LDS, 16B/lane
__device__ __forceinline__ void gload_lds16(const void* g, void* l) {
    __builtin_amdgcn_global_load_lds(
        (const __attribute__((address_space(1))) unsigned int*)(uintptr_t)g,
        (__attribute__((address_space(3))) unsigned int*)(unsigned int)(uintptr_t)l,
        16, 0, 0);
}

__device__ __forceinline__ unsigned int pack2h(float x, float y) {
    _Float16 hx = (_Float16)x, hy = (_Float16)y;
    unsigned short ux, uy;
    __builtin_memcpy(&ux, &hx, 2);
    __builtin_memcpy(&uy, &hy, 2);
    return (unsigned int)ux | ((unsigned int)uy << 16);
}

// ---------------- Kernel 0: fused fp16 convert + row norms + distance_pos ----
__global__ __launch_bounds__(256) void prep_kernel(
    const float* __restrict__ A, const float* __restrict__ P,
    const float* __restrict__ N, ushort* __restrict__ Xf,
    float* __restrict__ a2, float* __restrict__ p2,
    float* __restrict__ n2, float* __restrict__ dpos) {
    int row = (blockIdx.x * blockDim.x + threadIdx.x) >> 6;
    int lane = threadIdx.x & 63;
    if (row >= BDIM) return;
    const float2 av = *(const float2*)&A[row * DDIM + lane * 2];
    const float2 pv = *(const float2*)&P[row * DDIM + lane * 2];
    const float2 nv = *(const float2*)&N[row * DDIM + lane * 2];
    *(unsigned int*)&Xf[0 * MATSZ + row * DDIM + lane * 2] = pack2h(av.x, av.y);
    *(unsigned int*)&Xf[1 * MATSZ + row * DDIM + lane * 2] = pack2h(pv.x, pv.y);
    *(unsigned int*)&Xf[2 * MATSZ + row * DDIM + lane * 2] = pack2h(nv.x, nv.y);
    float sa = av.x * av.x + av.y * av.y;
    float sp = pv.x * pv.x + pv.y * pv.y;
    float sn = nv.x * nv.x + nv.y * nv.y;
    float dx = av.x - pv.x, dy = av.y - pv.y;
    float sd = dx * dx + dy * dy;
    #pragma unroll
    for (int off = 32; off; off >>= 1) {
        sa += __shfl_down(sa, off);
        sp += __shfl_down(sp, off);
        sn += __shfl_down(sn, off);
        sd += __shfl_down(sd, off);
    }
    if (lane == 0) {
        a2[row] = sa;
        p2[row] = sp;
        n2[row] = sn;
        dpos[row] = sqrtf(fmaxf(sd, EPSF));
    }
}

// stage one 64x128 fp16 tile into a linear LDS buffer; XOR-16-slot swizzle on
// the global source address (involution). 4 gload_lds per wave.
__device__ __forceinline__ void stage_Y(const ushort* g, int j0, ushort* dst,
                                        int w, int lane) {
    int sub = lane >> 4;
    int s = lane & 15;
    #pragma unroll
    for (int q = 0; q < 4; ++q) {
        int r = w * 16 + q * 4 + sub;
        int sp = s ^ (r & 15);
        gload_lds16(g + (size_t)(j0 + r) * DDIM + sp * 8,
                    dst + (w * 16 + q * 4) * DDIM);
    }
}

// ---------------- Kernel 1: fp16 MFMA min of (y2/2 - dot) ----------------
// grid (32 i-tiles, NSPLIT). 4 waves; wave = 64 rows x 32 cols (2 acc chains
// share each B fragment). 4 rotating Y buffers (A region reused), counted
// vmcnt, raw barriers, setprio around MFMA. NOTE: no min-waves clause —
// __launch_bounds__(256,2) caps arch VGPRs at ~128 on this compiler and
// silently spills (r9 evidence: WRITE_SIZE 105 MB, VGPR 84 at ",3").
__global__ __launch_bounds__(256) void minsq_kernel(
    const ushort* __restrict__ Xf,
    const float* __restrict__ a2, const float* __restrict__ p2,
    const float* __restrict__ n2, float* __restrict__ partial) {
    __shared__ __align__(16) ushort pool[4][YBUF];     // 64 KB -> 2 blocks/CU
    ushort* const base = &pool[0][0];

    const int tid = threadIdx.x;
    const int w = tid >> 6;
    const int lane = tid & 63;
    const int rg = w >> 1;    // 64-row group
    const int ch = w & 1;     // 32-col half
    const int iTile = blockIdx.x;
    const int split = blockIdx.y;
    const int i0 = iTile * TI;
    const int jt0 = split * JT;
    const int sub = lane >> 4, s = lane & 15;

    // stage A rows [i0, i0+128) into pool[0..1] (freed after fragment preload)
    #pragma unroll
    for (int q = 0; q < 8; ++q) {
        int r = w * 32 + q * 4 + sub;
        int sp = s ^ (r & 15);
        gload_lds16(Xf + (size_t)(i0 + r) * DDIM + sp * 8,
                    base + (w * 32 + q * 4) * DDIM);
    }
    // stage Y tiles t0 -> pool[2], t1 -> pool[3]
    stage_Y(Xf + (size_t)(jt0 >> 6) * MATSZ, (jt0 & 63) * TJ, base + 2 * YBUF, w, lane);
    stage_Y(Xf + (size_t)((jt0 + 1) >> 6) * MATSZ, ((jt0 + 1) & 63) * TJ,
            base + 3 * YBUF, w, lane);

    asm volatile("s_waitcnt vmcnt(8)" ::: "memory");   // my A loads done
    __builtin_amdgcn_s_barrier();                      // everyone's A done
    __builtin_amdgcn_sched_barrier(0);

    // preload this wave's A fragments: 2 row-blocks x 8 k-slices (64 VGPR)
    f16x8 afr[2][8];
    #pragma unroll
    for (int rb = 0; rb < 2; ++rb) {
        int r = rg * 64 + rb * 32 + (lane & 31);
        #pragma unroll
        for (int t = 0; t < 8; ++t) {
            int sl = t * 2 + (lane >> 5);
            int sp = sl ^ (r & 15);
            afr[rb][t] = *(const f16x8*)&base[r * DDIM + sp * 8];
        }
    }
    // preload per-tile y2/2 (removes global loads from the main loop)
    float y2h[JT];
    #pragma unroll
    for (int t = 0; t < JT; ++t) {
        int jt = jt0 + t, m = jt >> 6, tc = jt & 63;
        const float* y2g = (m == 0) ? a2 : ((m == 1) ? p2 : n2);
        y2h[t] = 0.5f * y2g[tc * TJ + ch * 32 + (lane & 31)];
    }
    asm volatile("s_waitcnt lgkmcnt(0)" ::: "memory"); // A-frag reads done
    __builtin_amdgcn_sched_barrier(0);
    __builtin_amdgcn_s_barrier();                      // pool[0..1] reusable
    __builtin_amdgcn_sched_barrier(0);

    float minv[2][16];
    #pragma unroll
    for (int rb = 0; rb < 2; ++rb)
        #pragma unroll
        for (int g = 0; g < 16; ++g) minv[rb][g] = FLT_BIG;

    #pragma unroll
    for (int idx = 0; idx < JT; ++idx) {
        // prefetch tile idx+2 into buffer (idx&3) — stays in flight over MFMA
        if (idx + 2 < JT) {
            int jn = jt0 + idx + 2;
            stage_Y(Xf + (size_t)(jn >> 6) * MATSZ, (jn & 63) * TJ,
                    base + (idx & 3) * YBUF, w, lane);
        }
        // counted vmcnt: ensure tile idx's 4 loads done, keep 8 in flight
        if (idx < JT - 2)       asm volatile("s_waitcnt vmcnt(8)" ::: "memory");
        else if (idx == JT - 2) asm volatile("s_waitcnt vmcnt(4)" ::: "memory");
        else                    asm volatile("s_waitcnt vmcnt(0)" ::: "memory");
        __builtin_amdgcn_s_barrier();
        __builtin_amdgcn_sched_barrier(0);

        const ushort* bufY = base + ((idx + 2) & 3) * YBUF;
        f32x16 acc0 = {};
        f32x16 acc1 = {};
        {
            int r = ch * 32 + (lane & 31);
            __builtin_amdgcn_s_setprio(1);
            #pragma unroll
            for (int t = 0; t < 8; ++t) {
                int sl = t * 2 + (lane >> 5);
                int sp = sl ^ (r & 15);
                f16x8 b = *(const f16x8*)&bufY[r * DDIM + sp * 8];
                acc0 = __builtin_amdgcn_mfma_f32_32x32x16_f16(afr[0][t], b, acc0, 0, 0, 0);
                acc1 = __builtin_amdgcn_mfma_f32_32x32x16_f16(afr[1][t], b, acc1, 0, 0, 0);
            }
            __builtin_amdgcn_s_setprio(0);
        }

        // epilogue: running min of (y2/2 - dot); diag exclusion on A/P mats
        {
            int jt = jt0 + idx, m = jt >> 6, tc = jt & 63;
            float yh = y2h[idx];
            if (m < 2 && (tc >> 1) == iTile) {
                int jg = tc * TJ + ch * 32 + (lane & 31);
                #pragma unroll
                for (int rb = 0; rb < 2; ++rb) {
                    #pragma unroll
                    for (int g = 0; g < 16; ++g) {
                        int rloc = (g & 3) + 8 * (g >> 2) + 4 * (lane >> 5);
                        int ig = i0 + rg * 64 + rb * 32 + rloc;
                        float d = (rb == 0) ? acc0[g] : acc1[g];
                        float cand = yh - d;
                        if (ig == jg) cand = FLT_BIG;
                        minv[rb][g] = fminf(minv[rb][g], cand);
                    }
                }
            } else {
                #pragma unroll
                for (int g = 0; g < 16; ++g) {
                    minv[0][g] = fminf(minv[0][g], yh - acc0[g]);
                    minv[1][g] = fminf(minv[1][g], yh - acc1[g]);
                }
            }
        }
    }

    // min over the 32 columns (within each 32-lane half)
    #pragma unroll
    for (int off = 1; off < 32; off <<= 1) {
        #pragma unroll
        for (int rb = 0; rb < 2; ++rb)
            #pragma unroll
            for (int g = 0; g < 16; ++g)
                minv[rb][g] = fminf(minv[rb][g], __shfl_xor(minv[rb][g], off));
    }
    // transposed partial layout: partial[row][slice]
    if ((lane & 31) == 0) {
        int hi = lane >> 5;
        int slice = split * 2 + ch;
        #pragma unroll
        for (int rb = 0; rb < 2; ++rb) {
            #pragma unroll
            for (int g = 0; g < 16; ++g) {
                int rloc = (g & 3) + 8 * (g >> 2) + 4 * hi;
                int ig = i0 + rg * 64 + rb * 32 + rloc;
                partial[(size_t)ig * NSLICE + slice] = minv[rb][g];
            }
        }
    }
}

// ---------------- Kernel 2a: per-row loss, 16-block partial sums ------------
__global__ __launch_bounds__(256) void lossA_kernel(
    const float* __restrict__ partial, const float* __restrict__ a2,
    const float* __restrict__ dpos, float* __restrict__ bsum) {
    __shared__ float red[4];
    int i = blockIdx.x * 256 + threadIdx.x;
    const float4* pr = (const float4*)&partial[(size_t)i * NSLICE];
    float mv = FLT_BIG;
    #pragma unroll
    for (int q = 0; q < NSLICE / 4; ++q) {
        float4 v = pr[q];
        mv = fminf(mv, fminf(fminf(v.x, v.y), fminf(v.z, v.w)));
    }
    float h2 = a2[i] + 2.0f * mv;
    float hardest = sqrtf(fmaxf(h2, EPSF));
    float x = dpos[i] - hardest;
    float sum = fmaxf(x, 0.f) + log1pf(expf(-fabsf(x)));
    #pragma unroll
    for (int off = 32; off; off >>= 1) sum += __shfl_down(sum, off);
    if ((threadIdx.x & 63) == 0) red[threadIdx.x >> 6] = sum;
    __syncthreads();
    if (threadIdx.x == 0)
        bsum[blockIdx.x] = red[0] + red[1] + red[2] + red[3];
}

// ---------------- Kernel 2b: final scalar ----------------
__global__ void lossB_kernel(const float* __restrict__ bsum,
                             float* __restrict__ out) {
    float v = (threadIdx.x < 16) ? bsum[threadIdx.x] : 0.f;
    #pragma unroll
    for (int off = 32; off; off >>= 1) v += __shfl_down(v, off);
    if (threadIdx.x == 0) out[0] = v * (1.0f / BDIM);
}

extern "C" void kernel_launch(void* const* d_in, const int* in_sizes, int n_in,
                              void* d_out, int out_size, void* d_ws, size_t ws_size,
                              hipStream_t stream) {
    const float* A = (const float*)d_in[0];
    const float* P = (const float*)d_in[1];
    const float* N = (const float*)d_in[2];

    float* ws = (float*)d_ws;
    float* a2 = ws;                          // 4096
    float* p2 = ws + BDIM;                   // 4096
    float* n2 = ws + 2 * BDIM;               // 4096
    float* dpos = ws + 3 * BDIM;             // 4096
    float* bsum = ws + 4 * BDIM;             // 64 (16 used)
    float* partial = ws + 4 * BDIM + 64;     // BDIM * NSLICE (transposed)
    ushort* Xf = (ushort*)(partial + (size_t)NSLICE * BDIM);  // 3*524288 fp16

    prep_kernel<<<BDIM / 4, 256, 0, stream>>>(A, P, N, Xf, a2, p2, n2, dpos);
    dim3 grid2(ITILES, NSPLIT);
    minsq_kernel<<<grid2, 256, 0, stream>>>(Xf, a2, p2, n2, partial);
    lossA_kernel<<<16, 256, 0, stream>>>(partial, a2, dpos, bsum);
    lossB_kernel<<<1, 64, 0, stream>>>(bsum, (float*)d_out);
}

// Round 11
// 35.997 us; speedup vs baseline: 2.5353x; 1.2003x over previous
//
#include <hip/hip_runtime.h>
#include <math.h>

#define BDIM 4096
#define DDIM 128
#define EPSF 1e-12f
#define TI 128
#define TJ 64
#define NSPLIT 16
#define NSLICE (NSPLIT * 2)                 // one slice per column-half wave
#define ITILES (BDIM / TI)                  // 32
#define JT 12                               // Y-tiles per split (16*12 = 192)
#define FLT_BIG 3.402823466e+38f
#define NCHUNK (16 * BDIM)                  // 16B chunks per matrix plane

typedef __attribute__((ext_vector_type(8))) _Float16 f16x8;
typedef __attribute__((ext_vector_type(16))) float f32x16;

// global (per-lane addr) -> linear LDS (wave-uniform base + lane*16), 16B/lane
__device__ __forceinline__ void gload_lds16(const void* g, void* l) {
    __builtin_amdgcn_global_load_lds(
        (const __attribute__((address_space(1))) unsigned int*)(uintptr_t)g,
        (__attribute__((address_space(3))) unsigned int*)(unsigned int)(uintptr_t)l,
        16, 0, 0);
}

__device__ __forceinline__ unsigned int pack2h(float x, float y) {
    _Float16 hx = (_Float16)x, hy = (_Float16)y;
    unsigned short ux, uy;
    __builtin_memcpy(&ux, &hx, 2);
    __builtin_memcpy(&uy, &hy, 2);
    return (unsigned int)ux | ((unsigned int)uy << 16);
}

// ---------------- Kernel 0: pack to MFMA-fragment layout + norms ------------
// Xp[mat][sl(16)][row(4096)] : 16B chunk = 8 fp16 (k = sl*8..sl*8+7) of row.
// Thread (sl,row) handles all 3 mats; 16-lane groups reduce row norms.
__global__ __launch_bounds__(256) void prep_kernel(
    const float* __restrict__ A, const float* __restrict__ P,
    const float* __restrict__ N, uint4* __restrict__ Xp,
    float* __restrict__ a2, float* __restrict__ p2,
    float* __restrict__ n2, float* __restrict__ dpos) {
    int gid = blockIdx.x * 256 + threadIdx.x;   // 0..65535
    int sl = gid & 15;
    int row = gid >> 4;
    const float4 a0 = *(const float4*)&A[row * DDIM + sl * 8];
    const float4 a1 = *(const float4*)&A[row * DDIM + sl * 8 + 4];
    const float4 p0 = *(const float4*)&P[row * DDIM + sl * 8];
    const float4 p1 = *(const float4*)&P[row * DDIM + sl * 8 + 4];
    const float4 n0 = *(const float4*)&N[row * DDIM + sl * 8];
    const float4 n1 = *(const float4*)&N[row * DDIM + sl * 8 + 4];
    uint4 ca = {pack2h(a0.x, a0.y), pack2h(a0.z, a0.w),
                pack2h(a1.x, a1.y), pack2h(a1.z, a1.w)};
    uint4 cp = {pack2h(p0.x, p0.y), pack2h(p0.z, p0.w),
                pack2h(p1.x, p1.y), pack2h(p1.z, p1.w)};
    uint4 cn = {pack2h(n0.x, n0.y), pack2h(n0.z, n0.w),
                pack2h(n1.x, n1.y), pack2h(n1.z, n1.w)};
    Xp[(0 * 16 + sl) * BDIM + row] = ca;
    Xp[(1 * 16 + sl) * BDIM + row] = cp;
    Xp[(2 * 16 + sl) * BDIM + row] = cn;
    float sa = a0.x*a0.x + a0.y*a0.y + a0.z*a0.z + a0.w*a0.w
             + a1.x*a1.x + a1.y*a1.y + a1.z*a1.z + a1.w*a1.w;
    float sp = p0.x*p0.x + p0.y*p0.y + p0.z*p0.z + p0.w*p0.w
             + p1.x*p1.x + p1.y*p1.y + p1.z*p1.z + p1.w*p1.w;
    float sn = n0.x*n0.x + n0.y*n0.y + n0.z*n0.z + n0.w*n0.w
             + n1.x*n1.x + n1.y*n1.y + n1.z*n1.z + n1.w*n1.w;
    float d0 = a0.x-p0.x, d1 = a0.y-p0.y, d2 = a0.z-p0.z, d3 = a0.w-p0.w;
    float d4 = a1.x-p1.x, d5 = a1.y-p1.y, d6 = a1.z-p1.z, d7 = a1.w-p1.w;
    float sd = d0*d0 + d1*d1 + d2*d2 + d3*d3 + d4*d4 + d5*d5 + d6*d6 + d7*d7;
    #pragma unroll
    for (int off = 1; off < 16; off <<= 1) {
        sa += __shfl_xor(sa, off);
        sp += __shfl_xor(sp, off);
        sn += __shfl_xor(sn, off);
        sd += __shfl_xor(sd, off);
    }
    if (sl == 0) {
        a2[row] = sa;
        p2[row] = sp;
        n2[row] = sn;
        dpos[row] = sqrtf(fmaxf(sd, EPSF));
    }
}

// ---------------- Kernel 1: fp16 MFMA min of (y2/2 - dot), ZERO barriers ----
// grid (32 i-tiles, 16 splits), 4 waves; wave = 64 rows x 32 cols. Each wave
// owns a private 2x8KB LDS slice and self-paces its B staging with counted
// vmcnt — no __syncthreads/s_barrier anywhere; waves hide each other's stalls.
__global__ __launch_bounds__(256, 2) void minsq_kernel(
    const ushort* __restrict__ Xp,
    const float* __restrict__ a2, const float* __restrict__ p2,
    const float* __restrict__ n2, float* __restrict__ partial) {
    __shared__ __align__(16) ushort pool[4][2][4096];   // 64 KB: 4 waves x 2 bufs

    const int tid = threadIdx.x;
    const int w = tid >> 6;
    const int lane = tid & 63;
    const int rg = w >> 1;    // 64-row group of the 128-row i-tile
    const int ch = w & 1;     // 32-col half of the 64-row Y tile
    const int iTile = blockIdx.x;
    const int split = blockIdx.y;
    const int i0 = iTile * TI;
    const int jt0 = split * JT;
    const int l31 = lane & 31;
    const int lhi = lane >> 5;
    ushort* const wbase = &pool[w][0][0];

    // ---- prologue: stage tile 0 -> buf0 (8 gload_lds) ----
    {
        int jt = jt0, m = jt >> 6, tc = jt & 63;
        int rowB = tc * TJ + ch * 32 + l31;
        #pragma unroll
        for (int k = 0; k < 8; ++k) {
            int slB = k * 2 + lhi;
            gload_lds16(Xp + (size_t)((m * 16 + slB) * BDIM + rowB) * 8,
                        wbase + k * 512);
        }
    }
    // A fragments direct from packed global (coalesced, L2-resident)
    f16x8 a0[8], a1[8];
    {
        int rowA0 = i0 + rg * 64 + l31;
        #pragma unroll
        for (int t = 0; t < 8; ++t) {
            int slA = t * 2 + lhi;
            a0[t] = *(const f16x8*)(Xp + (size_t)(slA * BDIM + rowA0) * 8);
            a1[t] = *(const f16x8*)(Xp + (size_t)(slA * BDIM + rowA0 + 32) * 8);
        }
    }
    // per-tile y2/2 for this wave's 32 columns
    float y2h[JT];
    #pragma unroll
    for (int t = 0; t < JT; ++t) {
        int jt = jt0 + t, m = jt >> 6, tc = jt & 63;
        const float* y2g = (m == 0) ? a2 : ((m == 1) ? p2 : n2);
        y2h[t] = 0.5f * y2g[tc * TJ + ch * 32 + l31];
    }
    // drain everything so in-loop vmcnt counts only staging loads
    asm volatile("s_waitcnt vmcnt(0)" ::: "memory");
    __builtin_amdgcn_sched_barrier(0);

    float minv[2][16];
    #pragma unroll
    for (int rb = 0; rb < 2; ++rb)
        #pragma unroll
        for (int g = 0; g < 16; ++g) minv[rb][g] = FLT_BIG;

    #pragma unroll
    for (int idx = 0; idx < JT; ++idx) {
        // issue next tile's staging into the other private buffer
        if (idx + 1 < JT) {
            int jn = jt0 + idx + 1, mn = jn >> 6, tcn = jn & 63;
            int rowB = tcn * TJ + ch * 32 + l31;
            ushort* dst = wbase + ((idx + 1) & 1) * 4096;
            #pragma unroll
            for (int k = 0; k < 8; ++k) {
                int slB = k * 2 + lhi;
                gload_lds16(Xp + (size_t)((mn * 16 + slB) * BDIM + rowB) * 8,
                            dst + k * 512);
            }
            asm volatile("s_waitcnt vmcnt(8)" ::: "memory");  // tile idx ready
        } else {
            asm volatile("s_waitcnt vmcnt(0)" ::: "memory");
        }
        __builtin_amdgcn_sched_barrier(0);

        const ushort* buf = wbase + (idx & 1) * 4096;
        f32x16 acc0 = {}, acc1 = {};
        __builtin_amdgcn_s_setprio(1);
        #pragma unroll
        for (int t = 0; t < 8; ++t) {
            f16x8 b = *(const f16x8*)&buf[t * 512 + lane * 8];
            acc0 = __builtin_amdgcn_mfma_f32_32x32x16_f16(a0[t], b, acc0, 0, 0, 0);
            acc1 = __builtin_amdgcn_mfma_f32_32x32x16_f16(a1[t], b, acc1, 0, 0, 0);
        }
        __builtin_amdgcn_s_setprio(0);

        // epilogue: running min of (y2/2 - dot); diag exclusion on A/P mats
        {
            int jt = jt0 + idx, m = jt >> 6, tc = jt & 63;
            float yh = y2h[idx];
            if (m < 2 && (tc >> 1) == iTile) {
                int jg = tc * TJ + ch * 32 + l31;
                #pragma unroll
                for (int rb = 0; rb < 2; ++rb) {
                    #pragma unroll
                    for (int g = 0; g < 16; ++g) {
                        int rloc = (g & 3) + 8 * (g >> 2) + 4 * lhi;
                        int ig = i0 + rg * 64 + rb * 32 + rloc;
                        float d = (rb == 0) ? acc0[g] : acc1[g];
                        float cand = yh - d;
                        if (ig == jg) cand = FLT_BIG;
                        minv[rb][g] = fminf(minv[rb][g], cand);
                    }
                }
            } else {
                #pragma unroll
                for (int g = 0; g < 16; ++g) {
                    minv[0][g] = fminf(minv[0][g], yh - acc0[g]);
                    minv[1][g] = fminf(minv[1][g], yh - acc1[g]);
                }
            }
        }
    }

    // min over the 32 columns (within each 32-lane half)
    #pragma unroll
    for (int off = 1; off < 32; off <<= 1) {
        #pragma unroll
        for (int rb = 0; rb < 2; ++rb)
            #pragma unroll
            for (int g = 0; g < 16; ++g)
                minv[rb][g] = fminf(minv[rb][g], __shfl_xor(minv[rb][g], off));
    }
    // transposed partial layout: partial[row][slice]
    if (l31 == 0) {
        int slice = split * 2 + ch;
        #pragma unroll
        for (int rb = 0; rb < 2; ++rb) {
            #pragma unroll
            for (int g = 0; g < 16; ++g) {
                int rloc = (g & 3) + 8 * (g >> 2) + 4 * lhi;
                int ig = i0 + rg * 64 + rb * 32 + rloc;
                partial[(size_t)ig * NSLICE + slice] = minv[rb][g];
            }
        }
    }
}

// ---------------- Kernel 2a: per-row loss, 16-block partial sums ------------
__global__ __launch_bounds__(256) void lossA_kernel(
    const float* __restrict__ partial, const float* __restrict__ a2,
    const float* __restrict__ dpos, float* __restrict__ bsum) {
    __shared__ float red[4];
    int i = blockIdx.x * 256 + threadIdx.x;
    const float4* pr = (const float4*)&partial[(size_t)i * NSLICE];
    float mv = FLT_BIG;
    #pragma unroll
    for (int q = 0; q < NSLICE / 4; ++q) {
        float4 v = pr[q];
        mv = fminf(mv, fminf(fminf(v.x, v.y), fminf(v.z, v.w)));
    }
    float h2 = a2[i] + 2.0f * mv;
    float hardest = sqrtf(fmaxf(h2, EPSF));
    float x = dpos[i] - hardest;
    float sum = fmaxf(x, 0.f) + log1pf(expf(-fabsf(x)));
    #pragma unroll
    for (int off = 32; off; off >>= 1) sum += __shfl_down(sum, off);
    if ((threadIdx.x & 63) == 0) red[threadIdx.x >> 6] = sum;
    __syncthreads();
    if (threadIdx.x == 0)
        bsum[blockIdx.x] = red[0] + red[1] + red[2] + red[3];
}

// ---------------- Kernel 2b: final scalar ----------------
__global__ void lossB_kernel(const float* __restrict__ bsum,
                             float* __restrict__ out) {
    float v = (threadIdx.x < 16) ? bsum[threadIdx.x] : 0.f;
    #pragma unroll
    for (int off = 32; off; off >>= 1) v += __shfl_down(v, off);
    if (threadIdx.x == 0) out[0] = v * (1.0f / BDIM);
}

extern "C" void kernel_launch(void* const* d_in, const int* in_sizes, int n_in,
                              void* d_out, int out_size, void* d_ws, size_t ws_size,
                              hipStream_t stream) {
    const float* A = (const float*)d_in[0];
    const float* P = (const float*)d_in[1];
    const float* N = (const float*)d_in[2];

    float* ws = (float*)d_ws;
    float* a2 = ws;                          // 4096
    float* p2 = ws + BDIM;                   // 4096
    float* n2 = ws + 2 * BDIM;               // 4096
    float* dpos = ws + 3 * BDIM;             // 4096
    float* bsum = ws + 4 * BDIM;             // 64 (16 used)
    float* partial = ws + 4 * BDIM + 64;     // BDIM * NSLICE (row-major)
    uint4* Xp = (uint4*)(partial + (size_t)BDIM * NSLICE);  // 3 * 16*4096 chunks

    prep_kernel<<<256, 256, 0, stream>>>(A, P, N, Xp, a2, p2, n2, dpos);
    dim3 grid2(ITILES, NSPLIT);
    minsq_kernel<<<grid2, 256, 0, stream>>>((const ushort*)Xp, a2, p2, n2, partial);
    lossA_kernel<<<16, 256, 0, stream>>>(partial, a2, dpos, bsum);
    lossB_kernel<<<1, 64, 0, stream>>>(bsum, (float*)d_out);
}